// Round 2
// baseline (191.756 us; speedup 1.0000x reference)
//
#include <hip/hip_runtime.h>
#include <math.h>

#define N_TOK 32768
#define DIM   512
#define NEXP  16
#define CAP   2457
#define CAPP  2464
#define NCHUNK 512   // chunks of 64 tokens

typedef __attribute__((ext_vector_type(8))) short   short8;
typedef __attribute__((ext_vector_type(4))) short   short4v;
typedef __attribute__((ext_vector_type(4))) float   floatx4;

__device__ __forceinline__ short f2bf(float f) {
  unsigned u = __builtin_bit_cast(unsigned, f);
  unsigned r = u + 0x7FFFu + ((u >> 16) & 1u);   // round-to-nearest-even bf16
  return (short)(r >> 16);
}
__device__ __forceinline__ float bf2f(short h) {
  return __builtin_bit_cast(float, ((unsigned)(unsigned short)h) << 16);
}

// ---------------- K1: MFMA router (split-bf16 hi/lo, 3-term) ----------------
#define LGP 17
__global__ __launch_bounds__(256) void router_k(
    const float* __restrict__ x, const float* __restrict__ sw,
    const float* __restrict__ sb, const float* __restrict__ ew,
    int* __restrict__ route, float* __restrict__ prob, int* __restrict__ hist,
    short* __restrict__ x_bf, short* __restrict__ w_bf) {
  __shared__ short swh[16][520];
  __shared__ short swl[16][520];
  __shared__ float lgt[64][LGP];
  __shared__ float sbs[NEXP];

  int tid = threadIdx.x;

  // folded convw: this block converts 2048 float4 of expert_w
  {
    const float4* src = (const float4*)ew;
    short4v* dst = (short4v*)w_bf;
    int base = blockIdx.x * 2048 + tid;
#pragma unroll
    for (int i = 0; i < 8; ++i) {
      float4 f = src[base + i * 256];
      short4v s;
      s[0] = f2bf(f.x); s[1] = f2bf(f.y); s[2] = f2bf(f.z); s[3] = f2bf(f.w);
      dst[base + i * 256] = s;
    }
  }

  // stage sw hi/lo into LDS
  {
    int idx = tid;
#pragma unroll
    for (int i = 0; i < 8; ++i, idx += 256) {
      int e = idx >> 7, k4 = idx & 127;
      float4 f = ((const float4*)(sw + e * DIM))[k4];
      short4v h, l;
      h[0] = f2bf(f.x); h[1] = f2bf(f.y); h[2] = f2bf(f.z); h[3] = f2bf(f.w);
      l[0] = f2bf(f.x - bf2f(h[0]));
      l[1] = f2bf(f.y - bf2f(h[1]));
      l[2] = f2bf(f.z - bf2f(h[2]));
      l[3] = f2bf(f.w - bf2f(h[3]));
      *(short4v*)&swh[e][k4 * 4] = h;
      *(short4v*)&swl[e][k4 * 4] = l;
    }
  }
  if (tid < NEXP) sbs[tid] = sb[tid];
  __syncthreads();

  int wv = tid >> 6, lane = tid & 63, q = lane >> 4, l16 = lane & 15;
  int row = blockIdx.x * 64 + wv * 16 + l16;
  const float* xr = x + (size_t)row * DIM;
  short* xbr = x_bf + (size_t)row * DIM;

  floatx4 acc = {};
#pragma unroll 4
  for (int kc = 0; kc < 16; ++kc) {
    int k0 = kc * 32 + q * 8;
    float4 f0 = *(const float4*)(xr + k0);
    float4 f1 = *(const float4*)(xr + k0 + 4);
    short8 hi, lo;
    hi[0] = f2bf(f0.x); hi[1] = f2bf(f0.y); hi[2] = f2bf(f0.z); hi[3] = f2bf(f0.w);
    hi[4] = f2bf(f1.x); hi[5] = f2bf(f1.y); hi[6] = f2bf(f1.z); hi[7] = f2bf(f1.w);
    lo[0] = f2bf(f0.x - bf2f(hi[0])); lo[1] = f2bf(f0.y - bf2f(hi[1]));
    lo[2] = f2bf(f0.z - bf2f(hi[2])); lo[3] = f2bf(f0.w - bf2f(hi[3]));
    lo[4] = f2bf(f1.x - bf2f(hi[4])); lo[5] = f2bf(f1.y - bf2f(hi[5]));
    lo[6] = f2bf(f1.z - bf2f(hi[6])); lo[7] = f2bf(f1.w - bf2f(hi[7]));
    *(short8*)(xbr + k0) = hi;
    short8 bh = *(const short8*)&swh[l16][k0];
    short8 bl = *(const short8*)&swl[l16][k0];
    acc = __builtin_amdgcn_mfma_f32_16x16x32_bf16(hi, bh, acc, 0, 0, 0);
    acc = __builtin_amdgcn_mfma_f32_16x16x32_bf16(lo, bh, acc, 0, 0, 0);
    acc = __builtin_amdgcn_mfma_f32_16x16x32_bf16(hi, bl, acc, 0, 0, 0);
  }
#pragma unroll
  for (int r = 0; r < 4; ++r)
    lgt[wv * 16 + q * 4 + r][l16] = acc[r];
  __syncthreads();

  if (tid < 64) {
    int t = blockIdx.x * 64 + tid;
    float lg[NEXP];
#pragma unroll
    for (int e = 0; e < NEXP; ++e) lg[e] = lgt[tid][e] + sbs[e];
    int arg = 0; float mx = lg[0];
#pragma unroll
    for (int e = 1; e < NEXP; ++e)
      if (lg[e] > mx) { mx = lg[e]; arg = e; }
    float s = 0.f;
#pragma unroll
    for (int e = 0; e < NEXP; ++e) s += expf(lg[e] - mx);
    route[t] = arg;
    prob[t]  = 1.0f / s;
#pragma unroll
    for (int e = 0; e < NEXP; ++e) {
      unsigned long long m = __ballot(arg == e);
      if (tid == e) hist[blockIdx.x * NEXP + e] = __popcll(m);
    }
  }
}

// ---------------- K2: positions + fused chunk-prefix scan -------------------
__global__ __launch_bounds__(256) void pos_k(
    const int* __restrict__ route, const float* __restrict__ prob,
    const int* __restrict__ hist, const float* __restrict__ x,
    float* __restrict__ out, int* __restrict__ lists,
    int* __restrict__ counts) {
  __shared__ int part[16][NEXP];
  __shared__ int base_s[NEXP];
  __shared__ int wcnt[4][NEXP];
  int tid = threadIdx.x;
  int b = blockIdx.x;
  int c0 = b * 4;
  {
    int g = tid >> 4, e = tid & 15;
    int s = 0;
    for (int c = g; c < c0; c += 16) s += hist[c * NEXP + e];
    part[g][e] = s;
  }
  __syncthreads();
  if (tid < NEXP) {
    int s = 0;
#pragma unroll
    for (int gg = 0; gg < 16; ++gg) s += part[gg][tid];
    base_s[tid] = s;
  }
  int wv = tid >> 6, lane = tid & 63;
  int t = b * 256 + wv * 64 + lane;
  int r = route[t];
  unsigned long long lower = (1ull << lane) - 1ull;
  int rank = 0;
#pragma unroll
  for (int e = 0; e < NEXP; ++e) {
    unsigned long long m = __ballot(r == e);
    if (r == e) rank = __popcll(m & lower);
    if (lane == e) wcnt[wv][e] = __popcll(m);
  }
  __syncthreads();
  int pre = base_s[r];
  for (int w2 = 0; w2 < wv; ++w2) pre += wcnt[w2][r];
  int pos = pre + rank;
  if (pos < CAP) {
    lists[r * CAPP + pos] = t;
  } else {
    float p = prob[t];
    const float4* xr = (const float4*)(x + (size_t)t * DIM);
    float4* o = (float4*)(out + (size_t)t * DIM);
    for (int d = 0; d < DIM / 4; ++d) {
      float4 v = xr[d];
      v.x *= p; v.y *= p; v.z *= p; v.w *= p;
      o[d] = v;
    }
  }
  if (b == 127 && tid < NEXP)
    counts[tid] = base_s[tid] + wcnt[0][tid] + wcnt[1][tid]
                + wcnt[2][tid] + wcnt[3][tid];
}

// ---------------- K3: grouped GEMM, 2-phase LDS double-buffer + XCD swizzle -
#define BM 64
#define BN 128
#define BKS 64
#define NWG_G 2496          // 4 x-blocks * 39 y-blocks * 16 experts
#define CPX_G 312           // NWG_G / 8 XCDs (exact)

#define GEMM_STAGE(b, k0)                                                     \
  {                                                                           \
    _Pragma("unroll")                                                         \
    for (int t2 = 0; t2 < 2; ++t2)                                            \
      __builtin_amdgcn_global_load_lds(                                       \
          (const __attribute__((address_space(1))) void*)(ga[t2] + (k0)),     \
          (__attribute__((address_space(3))) void*)(la[t2] + (b) * (BM*BKS)), \
          16, 0, 0);                                                          \
    _Pragma("unroll")                                                         \
    for (int t4 = 0; t4 < 4; ++t4)                                            \
      __builtin_amdgcn_global_load_lds(                                       \
          (const __attribute__((address_space(1))) void*)(gb[t4] + (k0)),     \
          (__attribute__((address_space(3))) void*)(lb[t4] + (b) * (BN*BKS)), \
          16, 0, 0);                                                          \
  }

#define GEMM_COMPUTE(b)                                                       \
  {                                                                           \
    _Pragma("unroll")                                                         \
    for (int kk = 0; kk < 2; ++kk) {                                          \
      short8 af[2], bfv[4];                                                   \
      int ckbase = kk * 4 + q;                                                \
      _Pragma("unroll")                                                       \
      for (int sm = 0; sm < 2; ++sm) {                                        \
        int row = wrow + sm * 16 + l16;                                       \
        int ph = ckbase ^ (row & 7);                                          \
        af[sm] = *(const short8*)&A_s[b][row * BKS + ph * 8];                 \
      }                                                                       \
      _Pragma("unroll")                                                       \
      for (int sn = 0; sn < 4; ++sn) {                                        \
        int row = wcol + sn * 16 + l16;                                       \
        int ph = ckbase ^ (row & 7);                                          \
        bfv[sn] = *(const short8*)&B_s[b][row * BKS + ph * 8];                \
      }                                                                       \
      _Pragma("unroll")                                                       \
      for (int sm = 0; sm < 2; ++sm)                                          \
        _Pragma("unroll")                                                     \
        for (int sn = 0; sn < 4; ++sn)                                        \
          acc[sm][sn] = __builtin_amdgcn_mfma_f32_16x16x32_bf16(              \
              af[sm], bfv[sn], acc[sm][sn], 0, 0, 0);                         \
    }                                                                         \
  }

__global__ __launch_bounds__(256, 3) void gemm_k(
    const short* __restrict__ x_bf, const short* __restrict__ w_bf,
    const float* __restrict__ eb, const int* __restrict__ lists,
    const int* __restrict__ counts, const float* __restrict__ prob,
    float* __restrict__ out) {
  // Bijective XCD swizzle: each XCD gets contiguous chunks of complete
  // 4-x-block groups (same A panel) -> A fetched once per XCD, not 4x.
  int orig = blockIdx.x;
  int wgid = (orig & 7) * CPX_G + (orig >> 3);
  int e    = wgid / 156;            // 156 = 4*39 blocks per expert
  int rem  = wgid - e * 156;
  int by   = rem >> 2;              // 39 y-blocks
  int bx   = rem & 3;               // 4 x-blocks (fastest -> same A panel adj)

  int cnt = counts[e]; if (cnt > CAP) cnt = CAP;
  int row0 = by * BM;
  if (row0 >= cnt) return;
  int col0 = bx * BN;

  __shared__ short A_s[2][BM * BKS];
  __shared__ short B_s[2][BN * BKS];
  __shared__ int rowtok[BM];

  int tid = threadIdx.x;
  if (tid < BM) {
    int gr = row0 + tid;
    rowtok[tid] = (gr < cnt) ? lists[e * CAPP + gr] : 0;
  }
  __syncthreads();

  int wv = tid >> 6, lane = tid & 63;
  int q = lane >> 4, l16 = lane & 15;
  int wrow = (wv >> 1) * 32, wcol = (wv & 1) * 64;

  // staging lane map: 8 rows x 8 chunks of 16B per wave-instruction
  int r_loc = lane >> 3, c = lane & 7;
  const short* ga[2]; short* la[2];
  const short* gb[4]; short* lb[4];
#pragma unroll
  for (int t2 = 0; t2 < 2; ++t2) {
    int row = wv * 16 + t2 * 8 + r_loc;
    int g = c ^ (row & 7);
    ga[t2] = x_bf + (size_t)rowtok[row] * DIM + g * 8;
    la[t2] = &A_s[0][(wv * 16 + t2 * 8) * BKS];     // wave-uniform base
  }
#pragma unroll
  for (int t4 = 0; t4 < 4; ++t4) {
    int row = wv * 32 + t4 * 8 + r_loc;
    int g = c ^ (row & 7);
    gb[t4] = w_bf + (size_t)(e * DIM + col0 + row) * DIM + g * 8;
    lb[t4] = &B_s[0][(wv * 32 + t4 * 8) * BKS];
  }

  floatx4 acc[2][4] = {};

  // 2-phase pipeline: stage next K-tile into other buffer BEFORE computing
  // current; one barrier per K-step (T3 minimum recipe).
  GEMM_STAGE(0, 0);
  __syncthreads();                       // drains vmcnt before barrier
#pragma unroll
  for (int k0 = 0; k0 < DIM; k0 += 2 * BKS) {
    GEMM_STAGE(1, k0 + BKS);             // k0+BKS <= 448 < DIM always
    GEMM_COMPUTE(0);
    __syncthreads();
    if (k0 + 2 * BKS < DIM)
      GEMM_STAGE(0, k0 + 2 * BKS);
    GEMM_COMPUTE(1);
    __syncthreads();
  }

#pragma unroll
  for (int sm = 0; sm < 2; ++sm) {
    int tt[4]; float pp[4]; int vld[4];
#pragma unroll
    for (int rg = 0; rg < 4; ++rg) {
      int rr = wrow + sm * 16 + q * 4 + rg;
      int gr = row0 + rr;
      vld[rg] = (gr < cnt);
      tt[rg]  = rowtok[rr];
      pp[rg]  = vld[rg] ? prob[tt[rg]] : 0.f;
    }
#pragma unroll
    for (int sn = 0; sn < 4; ++sn) {
      int col = col0 + wcol + sn * 16 + l16;
      float bias = eb[e * DIM + col];
#pragma unroll
      for (int rg = 0; rg < 4; ++rg)
        if (vld[rg])
          out[(size_t)tt[rg] * DIM + col] = (acc[sm][sn][rg] + bias) * pp[rg];
    }
  }
}

extern "C" void kernel_launch(void* const* d_in, const int* in_sizes, int n_in,
                              void* d_out, int out_size, void* d_ws, size_t ws_size,
                              hipStream_t stream) {
  const float* x  = (const float*)d_in[0];
  const float* sw = (const float*)d_in[1];
  const float* sb = (const float*)d_in[2];
  const float* ew = (const float*)d_in[3];
  const float* eb = (const float*)d_in[4];
  float* out = (float*)d_out;

  char* ws = (char*)d_ws;
  int*   route  = (int*)(ws + 0);
  float* prob   = (float*)(ws + 131072);
  int*   hist   = (int*)(ws + 262144);
  int*   counts = (int*)(ws + 327680);
  int*   lists  = (int*)(ws + 327744);
  short* x_bf   = (short*)(ws + (1 << 20));
  short* w_bf   = (short*)(ws + (1 << 20) + 33554432);

  hipLaunchKernelGGL(router_k, dim3(NCHUNK), dim3(256), 0, stream,
                     x, sw, sb, ew, route, prob, hist, x_bf, w_bf);
  hipLaunchKernelGGL(pos_k, dim3(128), dim3(256), 0, stream,
                     route, prob, hist, x, out, lists, counts);
  hipLaunchKernelGGL(gemm_k, dim3(NWG_G), dim3(256), 0, stream,
                     x_bf, w_bf, eb, lists, counts, prob, out);
}

// Round 5
// 180.724 us; speedup vs baseline: 1.0610x; 1.0610x over previous
//
#include <hip/hip_runtime.h>
#include <math.h>

#define N_TOK 32768
#define DIM   512
#define NEXP  16
#define CAP   2457
#define CAPP  2464
#define NCHUNK 512   // chunks of 64 tokens

typedef __attribute__((ext_vector_type(8))) short   short8;
typedef __attribute__((ext_vector_type(4))) short   short4v;
typedef __attribute__((ext_vector_type(4))) float   floatx4;

__device__ __forceinline__ short f2bf(float f) {
  unsigned u = __builtin_bit_cast(unsigned, f);
  unsigned r = u + 0x7FFFu + ((u >> 16) & 1u);   // round-to-nearest-even bf16
  return (short)(r >> 16);
}
__device__ __forceinline__ float bf2f(short h) {
  return __builtin_bit_cast(float, ((unsigned)(unsigned short)h) << 16);
}

// ---------------- K1: MFMA router (split-bf16 hi/lo, 3-term) ----------------
#define LGP 17
__global__ __launch_bounds__(256) void router_k(
    const float* __restrict__ x, const float* __restrict__ sw,
    const float* __restrict__ sb, const float* __restrict__ ew,
    int* __restrict__ route, float* __restrict__ prob, int* __restrict__ hist,
    short* __restrict__ x_bf, short* __restrict__ w_bf) {
  __shared__ short swh[16][520];
  __shared__ short swl[16][520];
  __shared__ float lgt[64][LGP];
  __shared__ float sbs[NEXP];

  int tid = threadIdx.x;

  // folded convw: this block converts 2048 float4 of expert_w
  {
    const float4* src = (const float4*)ew;
    short4v* dst = (short4v*)w_bf;
    int base = blockIdx.x * 2048 + tid;
#pragma unroll
    for (int i = 0; i < 8; ++i) {
      float4 f = src[base + i * 256];
      short4v s;
      s[0] = f2bf(f.x); s[1] = f2bf(f.y); s[2] = f2bf(f.z); s[3] = f2bf(f.w);
      dst[base + i * 256] = s;
    }
  }

  // stage sw hi/lo into LDS
  {
    int idx = tid;
#pragma unroll
    for (int i = 0; i < 8; ++i, idx += 256) {
      int e = idx >> 7, k4 = idx & 127;
      float4 f = ((const float4*)(sw + e * DIM))[k4];
      short4v h, l;
      h[0] = f2bf(f.x); h[1] = f2bf(f.y); h[2] = f2bf(f.z); h[3] = f2bf(f.w);
      l[0] = f2bf(f.x - bf2f(h[0]));
      l[1] = f2bf(f.y - bf2f(h[1]));
      l[2] = f2bf(f.z - bf2f(h[2]));
      l[3] = f2bf(f.w - bf2f(h[3]));
      *(short4v*)&swh[e][k4 * 4] = h;
      *(short4v*)&swl[e][k4 * 4] = l;
    }
  }
  if (tid < NEXP) sbs[tid] = sb[tid];
  __syncthreads();

  int wv = tid >> 6, lane = tid & 63, q = lane >> 4, l16 = lane & 15;
  int row = blockIdx.x * 64 + wv * 16 + l16;
  const float* xr = x + (size_t)row * DIM;
  short* xbr = x_bf + (size_t)row * DIM;

  floatx4 acc = {};
#pragma unroll 4
  for (int kc = 0; kc < 16; ++kc) {
    int k0 = kc * 32 + q * 8;
    float4 f0 = *(const float4*)(xr + k0);
    float4 f1 = *(const float4*)(xr + k0 + 4);
    short8 hi, lo;
    hi[0] = f2bf(f0.x); hi[1] = f2bf(f0.y); hi[2] = f2bf(f0.z); hi[3] = f2bf(f0.w);
    hi[4] = f2bf(f1.x); hi[5] = f2bf(f1.y); hi[6] = f2bf(f1.z); hi[7] = f2bf(f1.w);
    lo[0] = f2bf(f0.x - bf2f(hi[0])); lo[1] = f2bf(f0.y - bf2f(hi[1]));
    lo[2] = f2bf(f0.z - bf2f(hi[2])); lo[3] = f2bf(f0.w - bf2f(hi[3]));
    lo[4] = f2bf(f1.x - bf2f(hi[4])); lo[5] = f2bf(f1.y - bf2f(hi[5]));
    lo[6] = f2bf(f1.z - bf2f(hi[6])); lo[7] = f2bf(f1.w - bf2f(hi[7]));
    *(short8*)(xbr + k0) = hi;
    short8 bh = *(const short8*)&swh[l16][k0];
    short8 bl = *(const short8*)&swl[l16][k0];
    acc = __builtin_amdgcn_mfma_f32_16x16x32_bf16(hi, bh, acc, 0, 0, 0);
    acc = __builtin_amdgcn_mfma_f32_16x16x32_bf16(lo, bh, acc, 0, 0, 0);
    acc = __builtin_amdgcn_mfma_f32_16x16x32_bf16(hi, bl, acc, 0, 0, 0);
  }
#pragma unroll
  for (int r = 0; r < 4; ++r)
    lgt[wv * 16 + q * 4 + r][l16] = acc[r];
  __syncthreads();

  if (tid < 64) {
    int t = blockIdx.x * 64 + tid;
    float lg[NEXP];
#pragma unroll
    for (int e = 0; e < NEXP; ++e) lg[e] = lgt[tid][e] + sbs[e];
    int arg = 0; float mx = lg[0];
#pragma unroll
    for (int e = 1; e < NEXP; ++e)
      if (lg[e] > mx) { mx = lg[e]; arg = e; }
    float s = 0.f;
#pragma unroll
    for (int e = 0; e < NEXP; ++e) s += expf(lg[e] - mx);
    route[t] = arg;
    prob[t]  = 1.0f / s;
#pragma unroll
    for (int e = 0; e < NEXP; ++e) {
      unsigned long long m = __ballot(arg == e);
      if (tid == e) hist[blockIdx.x * NEXP + e] = __popcll(m);
    }
  }
}

// ---------------- K2: positions + fused chunk-prefix scan -------------------
__global__ __launch_bounds__(256) void pos_k(
    const int* __restrict__ route, const float* __restrict__ prob,
    const int* __restrict__ hist, const float* __restrict__ x,
    float* __restrict__ out, int* __restrict__ lists,
    int* __restrict__ counts) {
  __shared__ int part[16][NEXP];
  __shared__ int base_s[NEXP];
  __shared__ int wcnt[4][NEXP];
  int tid = threadIdx.x;
  int b = blockIdx.x;
  int c0 = b * 4;
  {
    int g = tid >> 4, e = tid & 15;
    int s = 0;
    for (int c = g; c < c0; c += 16) s += hist[c * NEXP + e];
    part[g][e] = s;
  }
  __syncthreads();
  if (tid < NEXP) {
    int s = 0;
#pragma unroll
    for (int gg = 0; gg < 16; ++gg) s += part[gg][tid];
    base_s[tid] = s;
  }
  int wv = tid >> 6, lane = tid & 63;
  int t = b * 256 + wv * 64 + lane;
  int r = route[t];
  unsigned long long lower = (1ull << lane) - 1ull;
  int rank = 0;
#pragma unroll
  for (int e = 0; e < NEXP; ++e) {
    unsigned long long m = __ballot(r == e);
    if (r == e) rank = __popcll(m & lower);
    if (lane == e) wcnt[wv][e] = __popcll(m);
  }
  __syncthreads();
  int pre = base_s[r];
  for (int w2 = 0; w2 < wv; ++w2) pre += wcnt[w2][r];
  int pos = pre + rank;
  if (pos < CAP) {
    lists[r * CAPP + pos] = t;
  } else {
    float p = prob[t];
    const float4* xr = (const float4*)(x + (size_t)t * DIM);
    float4* o = (float4*)(out + (size_t)t * DIM);
    for (int d = 0; d < DIM / 4; ++d) {
      float4 v = xr[d];
      v.x *= p; v.y *= p; v.z *= p; v.w *= p;
      o[d] = v;
    }
  }
  if (b == 127 && tid < NEXP)
    counts[tid] = base_s[tid] + wcnt[0][tid] + wcnt[1][tid]
                + wcnt[2][tid] + wcnt[3][tid];
}

// ---- K3: grouped GEMM, 128x128 tile, single-buffer m97 structure, XCD swz --
#define BM 128
#define BN 128
#define BKS 64
#define TPE 80              // tiles per expert: 20 y * 4 x
#define NWG_G (TPE * NEXP)  // 1280
#define CPX_G (NWG_G / 8)   // 160 (exact)

__global__ __launch_bounds__(256, 3) void gemm_k(
    const short* __restrict__ x_bf, const short* __restrict__ w_bf,
    const float* __restrict__ eb, const int* __restrict__ lists,
    const int* __restrict__ counts, const float* __restrict__ prob,
    float* __restrict__ out) {
  // Bijective XCD swizzle: XCD x owns wgid [x*160,(x+1)*160) = 2 experts.
  // bx fastest -> 4 consecutive blocks share one A panel (L2-hit).
  int orig = blockIdx.x;
  int wgid = (orig & 7) * CPX_G + (orig >> 3);
  int e    = wgid / TPE;
  int rem  = wgid - e * TPE;
  int by   = rem >> 2;              // 20 y-blocks
  int bx   = rem & 3;               // 4 x-blocks

  int cnt = counts[e]; if (cnt > CAP) cnt = CAP;
  int row0 = by * BM;
  if (row0 >= cnt) return;
  int col0 = bx * BN;

  __shared__ short A_s[BM * BKS];
  __shared__ short B_s[BN * BKS];
  __shared__ int rowtok[BM];

  int tid = threadIdx.x;
  if (tid < BM) {
    int gr = row0 + tid;
    rowtok[tid] = (gr < cnt) ? lists[e * CAPP + gr] : 0;
  }
  __syncthreads();

  int wv = tid >> 6, lane = tid & 63;
  int q = lane >> 4, l16 = lane & 15;
  int wrow = (wv & 2) * 32, wcol = (wv & 1) * 64;   // 2x2 wave grid of 64x64

  // staging lane map: 8 rows x 8 chunks of 16B per wave-instruction
  int r_loc = lane >> 3, c = lane & 7;
  const short* ga[4]; short* la[4];
  const short* gb[4]; short* lb[4];
#pragma unroll
  for (int t4 = 0; t4 < 4; ++t4) {
    int row = wv * 32 + t4 * 8 + r_loc;
    int g = c ^ (row & 7);
    ga[t4] = x_bf + (size_t)rowtok[row] * DIM + g * 8;
    la[t4] = &A_s[(wv * 32 + t4 * 8) * BKS];     // wave-uniform base
    gb[t4] = w_bf + (size_t)(e * DIM + col0 + row) * DIM + g * 8;
    lb[t4] = &B_s[(wv * 32 + t4 * 8) * BKS];
  }

  floatx4 acc[4][4] = {};

  for (int k0 = 0; k0 < DIM; k0 += BKS) {
#pragma unroll
    for (int t4 = 0; t4 < 4; ++t4)
      __builtin_amdgcn_global_load_lds(
          (const __attribute__((address_space(1))) void*)(ga[t4] + k0),
          (__attribute__((address_space(3))) void*)(la[t4]), 16, 0, 0);
#pragma unroll
    for (int t4 = 0; t4 < 4; ++t4)
      __builtin_amdgcn_global_load_lds(
          (const __attribute__((address_space(1))) void*)(gb[t4] + k0),
          (__attribute__((address_space(3))) void*)(lb[t4]), 16, 0, 0);
    __syncthreads();
#pragma unroll
    for (int kk = 0; kk < 2; ++kk) {
      short8 af[4], bfv[4];
      int ckbase = kk * 4 + q;
#pragma unroll
      for (int sm = 0; sm < 4; ++sm) {
        int row = wrow + sm * 16 + l16;
        int ph = ckbase ^ (row & 7);
        af[sm] = *(const short8*)&A_s[row * BKS + ph * 8];
      }
#pragma unroll
      for (int sn = 0; sn < 4; ++sn) {
        int row = wcol + sn * 16 + l16;
        int ph = ckbase ^ (row & 7);
        bfv[sn] = *(const short8*)&B_s[row * BKS + ph * 8];
      }
#pragma unroll
      for (int sm = 0; sm < 4; ++sm)
#pragma unroll
        for (int sn = 0; sn < 4; ++sn)
          acc[sm][sn] = __builtin_amdgcn_mfma_f32_16x16x32_bf16(
              af[sm], bfv[sn], acc[sm][sn], 0, 0, 0);
    }
    __syncthreads();
  }

#pragma unroll
  for (int sm = 0; sm < 4; ++sm) {
    int tt[4]; float pp[4]; int vld[4];
#pragma unroll
    for (int rg = 0; rg < 4; ++rg) {
      int rr = wrow + sm * 16 + q * 4 + rg;
      int gr = row0 + rr;
      vld[rg] = (gr < cnt);
      tt[rg]  = rowtok[rr];
      pp[rg]  = vld[rg] ? prob[tt[rg]] : 0.f;
    }
#pragma unroll
    for (int sn = 0; sn < 4; ++sn) {
      int col = col0 + wcol + sn * 16 + l16;
      float bias = eb[e * DIM + col];
#pragma unroll
      for (int rg = 0; rg < 4; ++rg)
        if (vld[rg])
          out[(size_t)tt[rg] * DIM + col] = (acc[sm][sn][rg] + bias) * pp[rg];
    }
  }
}

extern "C" void kernel_launch(void* const* d_in, const int* in_sizes, int n_in,
                              void* d_out, int out_size, void* d_ws, size_t ws_size,
                              hipStream_t stream) {
  const float* x  = (const float*)d_in[0];
  const float* sw = (const float*)d_in[1];
  const float* sb = (const float*)d_in[2];
  const float* ew = (const float*)d_in[3];
  const float* eb = (const float*)d_in[4];
  float* out = (float*)d_out;

  char* ws = (char*)d_ws;
  int*   route  = (int*)(ws + 0);
  float* prob   = (float*)(ws + 131072);
  int*   hist   = (int*)(ws + 262144);
  int*   counts = (int*)(ws + 327680);
  int*   lists  = (int*)(ws + 327744);
  short* x_bf   = (short*)(ws + (1 << 20));
  short* w_bf   = (short*)(ws + (1 << 20) + 33554432);

  hipLaunchKernelGGL(router_k, dim3(NCHUNK), dim3(256), 0, stream,
                     x, sw, sb, ew, route, prob, hist, x_bf, w_bf);
  hipLaunchKernelGGL(pos_k, dim3(128), dim3(256), 0, stream,
                     route, prob, hist, x, out, lists, counts);
  hipLaunchKernelGGL(gemm_k, dim3(NWG_G), dim3(256), 0, stream,
                     x_bf, w_bf, eb, lists, counts, prob, out);
}

// Round 6
// 180.460 us; speedup vs baseline: 1.0626x; 1.0015x over previous
//
#include <hip/hip_runtime.h>
#include <math.h>

#define N_TOK 32768
#define DIM   512
#define NEXP  16
#define CAP   2457
#define CAPP  2464
#define NCHUNK 512   // chunks of 64 tokens

typedef __attribute__((ext_vector_type(8))) short   short8;
typedef __attribute__((ext_vector_type(4))) short   short4v;
typedef __attribute__((ext_vector_type(4))) float   floatx4;
typedef __attribute__((ext_vector_type(4))) unsigned uint4v;

__device__ __forceinline__ short f2bf(float f) {
  unsigned u = __builtin_bit_cast(unsigned, f);
  unsigned r = u + 0x7FFFu + ((u >> 16) & 1u);   // round-to-nearest-even bf16
  return (short)(r >> 16);
}
__device__ __forceinline__ float bf2f(short h) {
  return __builtin_bit_cast(float, ((unsigned)(unsigned short)h) << 16);
}

// HW packed bf16 convert (RNE): lo16 = bf16(a), hi16 = bf16(b). 1 instr for 2 vals.
__device__ __forceinline__ unsigned cvt_pk(float a, float b) {
  unsigned r;
  asm("v_cvt_pk_bf16_f32 %0, %1, %2" : "=v"(r) : "v"(a), "v"(b));
  return r;
}
// reconstruct f32 of the two packed bf16 halves (1 VALU op each)
__device__ __forceinline__ float pklo(unsigned h) {
  return __builtin_bit_cast(float, h << 16);
}
__device__ __forceinline__ float pkhi(unsigned h) {
  return __builtin_bit_cast(float, h & 0xFFFF0000u);
}

// ---------------- K1: MFMA router (split-bf16 hi/lo, 3-term) ----------------
#define LGP 17
__global__ __launch_bounds__(256) void router_k(
    const float* __restrict__ x, const float* __restrict__ sw,
    const float* __restrict__ sb, const float* __restrict__ ew,
    int* __restrict__ route, float* __restrict__ prob, int* __restrict__ hist,
    short* __restrict__ x_bf, short* __restrict__ w_bf) {
  __shared__ short swh[16][520];
  __shared__ short swl[16][520];
  __shared__ float lgt[64][LGP];
  __shared__ float sbs[NEXP];

  int tid = threadIdx.x;

  // folded convw: this block converts 2048 float4 of expert_w (cvt_pk: 2 ops/float4)
  {
    const float4* src = (const float4*)ew;
    uint2* dst = (uint2*)w_bf;
    int base = blockIdx.x * 2048 + tid;
#pragma unroll
    for (int i = 0; i < 8; ++i) {
      float4 f = src[base + i * 256];
      uint2 s;
      s.x = cvt_pk(f.x, f.y);
      s.y = cvt_pk(f.z, f.w);
      dst[base + i * 256] = s;
    }
  }

  // stage sw hi/lo into LDS
  {
    int idx = tid;
#pragma unroll
    for (int i = 0; i < 8; ++i, idx += 256) {
      int e = idx >> 7, k4 = idx & 127;
      float4 f = ((const float4*)(sw + e * DIM))[k4];
      unsigned h0 = cvt_pk(f.x, f.y);
      unsigned h1 = cvt_pk(f.z, f.w);
      unsigned l0 = cvt_pk(f.x - pklo(h0), f.y - pkhi(h0));
      unsigned l1 = cvt_pk(f.z - pklo(h1), f.w - pkhi(h1));
      uint2 hv; hv.x = h0; hv.y = h1;
      uint2 lv; lv.x = l0; lv.y = l1;
      *(uint2*)&swh[e][k4 * 4] = hv;
      *(uint2*)&swl[e][k4 * 4] = lv;
    }
  }
  if (tid < NEXP) sbs[tid] = sb[tid];
  __syncthreads();

  int wv = tid >> 6, lane = tid & 63, q = lane >> 4, l16 = lane & 15;
  int row = blockIdx.x * 64 + wv * 16 + l16;
  const float* xr = x + (size_t)row * DIM;
  short* xbr = x_bf + (size_t)row * DIM;

  floatx4 acc = {};
#pragma unroll 4
  for (int kc = 0; kc < 16; ++kc) {
    int k0 = kc * 32 + q * 8;
    float4 f0 = *(const float4*)(xr + k0);
    float4 f1 = *(const float4*)(xr + k0 + 4);
    unsigned h0 = cvt_pk(f0.x, f0.y);
    unsigned h1 = cvt_pk(f0.z, f0.w);
    unsigned h2 = cvt_pk(f1.x, f1.y);
    unsigned h3 = cvt_pk(f1.z, f1.w);
    unsigned l0 = cvt_pk(f0.x - pklo(h0), f0.y - pkhi(h0));
    unsigned l1 = cvt_pk(f0.z - pklo(h1), f0.w - pkhi(h1));
    unsigned l2 = cvt_pk(f1.x - pklo(h2), f1.y - pkhi(h2));
    unsigned l3 = cvt_pk(f1.z - pklo(h3), f1.w - pkhi(h3));
    uint4v hp = {h0, h1, h2, h3};
    uint4v lp = {l0, l1, l2, l3};
    short8 hi = __builtin_bit_cast(short8, hp);
    short8 lo = __builtin_bit_cast(short8, lp);
    *(short8*)(xbr + k0) = hi;
    short8 bh = *(const short8*)&swh[l16][k0];
    short8 bl = *(const short8*)&swl[l16][k0];
    acc = __builtin_amdgcn_mfma_f32_16x16x32_bf16(hi, bh, acc, 0, 0, 0);
    acc = __builtin_amdgcn_mfma_f32_16x16x32_bf16(lo, bh, acc, 0, 0, 0);
    acc = __builtin_amdgcn_mfma_f32_16x16x32_bf16(hi, bl, acc, 0, 0, 0);
  }
#pragma unroll
  for (int r = 0; r < 4; ++r)
    lgt[wv * 16 + q * 4 + r][l16] = acc[r];
  __syncthreads();

  if (tid < 64) {
    int t = blockIdx.x * 64 + tid;
    float lg[NEXP];
#pragma unroll
    for (int e = 0; e < NEXP; ++e) lg[e] = lgt[tid][e] + sbs[e];
    int arg = 0; float mx = lg[0];
#pragma unroll
    for (int e = 1; e < NEXP; ++e)
      if (lg[e] > mx) { mx = lg[e]; arg = e; }
    float s = 0.f;
#pragma unroll
    for (int e = 0; e < NEXP; ++e) s += expf(lg[e] - mx);
    route[t] = arg;
    prob[t]  = 1.0f / s;
#pragma unroll
    for (int e = 0; e < NEXP; ++e) {
      unsigned long long m = __ballot(arg == e);
      if (tid == e) hist[blockIdx.x * NEXP + e] = __popcll(m);
    }
  }
}

// ---------------- K2: positions + fused chunk-prefix scan -------------------
__global__ __launch_bounds__(256) void pos_k(
    const int* __restrict__ route, const float* __restrict__ prob,
    const int* __restrict__ hist, const float* __restrict__ x,
    float* __restrict__ out, int* __restrict__ lists,
    int* __restrict__ counts) {
  __shared__ int part[16][NEXP];
  __shared__ int base_s[NEXP];
  __shared__ int wcnt[4][NEXP];
  int tid = threadIdx.x;
  int b = blockIdx.x;
  int c0 = b * 4;
  {
    int g = tid >> 4, e = tid & 15;
    int s = 0;
    for (int c = g; c < c0; c += 16) s += hist[c * NEXP + e];
    part[g][e] = s;
  }
  __syncthreads();
  if (tid < NEXP) {
    int s = 0;
#pragma unroll
    for (int gg = 0; gg < 16; ++gg) s += part[gg][tid];
    base_s[tid] = s;
  }
  int wv = tid >> 6, lane = tid & 63;
  int t = b * 256 + wv * 64 + lane;
  int r = route[t];
  unsigned long long lower = (1ull << lane) - 1ull;
  int rank = 0;
#pragma unroll
  for (int e = 0; e < NEXP; ++e) {
    unsigned long long m = __ballot(r == e);
    if (r == e) rank = __popcll(m & lower);
    if (lane == e) wcnt[wv][e] = __popcll(m);
  }
  __syncthreads();
  int pre = base_s[r];
  for (int w2 = 0; w2 < wv; ++w2) pre += wcnt[w2][r];
  int pos = pre + rank;
  if (pos < CAP) {
    lists[r * CAPP + pos] = t;
  } else {
    float p = prob[t];
    const float4* xr = (const float4*)(x + (size_t)t * DIM);
    float4* o = (float4*)(out + (size_t)t * DIM);
    for (int d = 0; d < DIM / 4; ++d) {
      float4 v = xr[d];
      v.x *= p; v.y *= p; v.z *= p; v.w *= p;
      o[d] = v;
    }
  }
  if (b == 127 && tid < NEXP)
    counts[tid] = base_s[tid] + wcnt[0][tid] + wcnt[1][tid]
                + wcnt[2][tid] + wcnt[3][tid];
}

// ---- K3: grouped GEMM, 128x128 tile, single-buffer m97 structure, XCD swz --
#define BM 128
#define BN 128
#define BKS 64
#define TPE 80              // tiles per expert: 20 y * 4 x
#define NWG_G (TPE * NEXP)  // 1280
#define CPX_G (NWG_G / 8)   // 160 (exact)

__global__ __launch_bounds__(256, 3) void gemm_k(
    const short* __restrict__ x_bf, const short* __restrict__ w_bf,
    const float* __restrict__ eb, const int* __restrict__ lists,
    const int* __restrict__ counts, const float* __restrict__ prob,
    float* __restrict__ out) {
  // Bijective XCD swizzle: XCD x owns wgid [x*160,(x+1)*160) = 2 experts.
  // bx fastest -> 4 consecutive blocks share one A panel (L2-hit).
  int orig = blockIdx.x;
  int wgid = (orig & 7) * CPX_G + (orig >> 3);
  int e    = wgid / TPE;
  int rem  = wgid - e * TPE;
  int by   = rem >> 2;              // 20 y-blocks
  int bx   = rem & 3;               // 4 x-blocks

  int cnt = counts[e]; if (cnt > CAP) cnt = CAP;
  int row0 = by * BM;
  if (row0 >= cnt) return;
  int col0 = bx * BN;

  __shared__ short A_s[BM * BKS];
  __shared__ short B_s[BN * BKS];
  __shared__ int rowtok[BM];

  int tid = threadIdx.x;
  if (tid < BM) {
    int gr = row0 + tid;
    rowtok[tid] = (gr < cnt) ? lists[e * CAPP + gr] : 0;
  }
  __syncthreads();

  int wv = tid >> 6, lane = tid & 63;
  int q = lane >> 4, l16 = lane & 15;
  int wrow = (wv & 2) * 32, wcol = (wv & 1) * 64;   // 2x2 wave grid of 64x64

  // staging lane map: 8 rows x 8 chunks of 16B per wave-instruction
  int r_loc = lane >> 3, c = lane & 7;
  const short* ga[4]; short* la[4];
  const short* gb[4]; short* lb[4];
#pragma unroll
  for (int t4 = 0; t4 < 4; ++t4) {
    int row = wv * 32 + t4 * 8 + r_loc;
    int g = c ^ (row & 7);
    ga[t4] = x_bf + (size_t)rowtok[row] * DIM + g * 8;
    la[t4] = &A_s[(wv * 32 + t4 * 8) * BKS];     // wave-uniform base
    gb[t4] = w_bf + (size_t)(e * DIM + col0 + row) * DIM + g * 8;
    lb[t4] = &B_s[(wv * 32 + t4 * 8) * BKS];
  }

  floatx4 acc[4][4] = {};

  for (int k0 = 0; k0 < DIM; k0 += BKS) {
#pragma unroll
    for (int t4 = 0; t4 < 4; ++t4)
      __builtin_amdgcn_global_load_lds(
          (const __attribute__((address_space(1))) void*)(ga[t4] + k0),
          (__attribute__((address_space(3))) void*)(la[t4]), 16, 0, 0);
#pragma unroll
    for (int t4 = 0; t4 < 4; ++t4)
      __builtin_amdgcn_global_load_lds(
          (const __attribute__((address_space(1))) void*)(gb[t4] + k0),
          (__attribute__((address_space(3))) void*)(lb[t4]), 16, 0, 0);
    __syncthreads();
#pragma unroll
    for (int kk = 0; kk < 2; ++kk) {
      short8 af[4], bfv[4];
      int ckbase = kk * 4 + q;
#pragma unroll
      for (int sm = 0; sm < 4; ++sm) {
        int row = wrow + sm * 16 + l16;
        int ph = ckbase ^ (row & 7);
        af[sm] = *(const short8*)&A_s[row * BKS + ph * 8];
      }
#pragma unroll
      for (int sn = 0; sn < 4; ++sn) {
        int row = wcol + sn * 16 + l16;
        int ph = ckbase ^ (row & 7);
        bfv[sn] = *(const short8*)&B_s[row * BKS + ph * 8];
      }
#pragma unroll
      for (int sm = 0; sm < 4; ++sm)
#pragma unroll
        for (int sn = 0; sn < 4; ++sn)
          acc[sm][sn] = __builtin_amdgcn_mfma_f32_16x16x32_bf16(
              af[sm], bfv[sn], acc[sm][sn], 0, 0, 0);
    }
    __syncthreads();
  }

#pragma unroll
  for (int sm = 0; sm < 4; ++sm) {
    int tt[4]; float pp[4]; int vld[4];
#pragma unroll
    for (int rg = 0; rg < 4; ++rg) {
      int rr = wrow + sm * 16 + q * 4 + rg;
      int gr = row0 + rr;
      vld[rg] = (gr < cnt);
      tt[rg]  = rowtok[rr];
      pp[rg]  = vld[rg] ? prob[tt[rg]] : 0.f;
    }
#pragma unroll
    for (int sn = 0; sn < 4; ++sn) {
      int col = col0 + wcol + sn * 16 + l16;
      float bias = eb[e * DIM + col];
#pragma unroll
      for (int rg = 0; rg < 4; ++rg)
        if (vld[rg])
          out[(size_t)tt[rg] * DIM + col] = (acc[sm][sn][rg] + bias) * pp[rg];
    }
  }
}

extern "C" void kernel_launch(void* const* d_in, const int* in_sizes, int n_in,
                              void* d_out, int out_size, void* d_ws, size_t ws_size,
                              hipStream_t stream) {
  const float* x  = (const float*)d_in[0];
  const float* sw = (const float*)d_in[1];
  const float* sb = (const float*)d_in[2];
  const float* ew = (const float*)d_in[3];
  const float* eb = (const float*)d_in[4];
  float* out = (float*)d_out;

  char* ws = (char*)d_ws;
  int*   route  = (int*)(ws + 0);
  float* prob   = (float*)(ws + 131072);
  int*   hist   = (int*)(ws + 262144);
  int*   counts = (int*)(ws + 327680);
  int*   lists  = (int*)(ws + 327744);
  short* x_bf   = (short*)(ws + (1 << 20));
  short* w_bf   = (short*)(ws + (1 << 20) + 33554432);

  hipLaunchKernelGGL(router_k, dim3(NCHUNK), dim3(256), 0, stream,
                     x, sw, sb, ew, route, prob, hist, x_bf, w_bf);
  hipLaunchKernelGGL(pos_k, dim3(128), dim3(256), 0, stream,
                     route, prob, hist, x, out, lists, counts);
  hipLaunchKernelGGL(gemm_k, dim3(NWG_G), dim3(256), 0, stream,
                     x_bf, w_bf, eb, lists, counts, prob, out);
}